// Round 14
// baseline (4417.076 us; speedup 1.0000x reference)
//
#include <hip/hip_runtime.h>

#define NT 64
#define GPB 32
#define NB 262144

struct P {
  const float* node_feat; const float* edge_feat; const int* ei;
  const float* W_ne; const float* b_ne; const float* g_ne; const float* be_ne;
  const float* W_ee; const float* b_ee;
  const float* msg_W1; const float* msg_b1; const float* msg_W2; const float* msg_b2;
  const float* upd_W1; const float* upd_b1; const float* upd_g1; const float* upd_be1;
  const float* upd_W2; const float* upd_b2; const float* upd_g2; const float* upd_be2;
  const float* Wp; const float* bp; const float* gp; const float* bep;
  const float* mW1; const float* mb1; const float* mg1; const float* mbe1;
  const float* mW2; const float* mb2; const float* mg2; const float* mbe2;
  const float* mW3; const float* mb3; const float* mg3; const float* mbe3;
  const float* mW4; const float* mb4;
  float* out;
};

// 1/sqrt(1+1e-5)
#define INVC 0.9999950000374997f

__device__ __forceinline__ float sigm(float x) {
  return __builtin_amdgcn_rcpf(1.0f + __expf(-x));
}

// exchange within lane pairs (2p <-> 2p+1): quad_perm [1,0,3,2] = 0xB1 (R5-verified)
__device__ __forceinline__ float dpp_xor1(float v) {
  return __builtin_bit_cast(float, __builtin_amdgcn_update_dpp(
      0, __builtin_bit_cast(int, v), 0xB1, 0xF, 0xF, false));
}

__device__ __forceinline__ float4 ld4(const float* p_) { return *(const float4*)p_; }

__device__ __forceinline__ void fma8(float hv, const float4 w0, const float4 w1,
                                     float (&a)[8]) {
  a[0] = fmaf(hv, w0.x, a[0]); a[1] = fmaf(hv, w0.y, a[1]);
  a[2] = fmaf(hv, w0.z, a[2]); a[3] = fmaf(hv, w0.w, a[3]);
  a[4] = fmaf(hv, w1.x, a[4]); a[5] = fmaf(hv, w1.y, a[5]);
  a[6] = fmaf(hv, w1.z, a[6]); a[7] = fmaf(hv, w1.w, a[7]);
}

// Register-h variant (h already in VGPRs): acc[8] += W[k][d0..d0+7]^T · h[k].
template <int K, int LD>
__device__ __forceinline__ void gemm8(const float* Wd, const float (&h)[K],
                                      float (&a)[8]) {
  constexpr int NC = K / 2;
  static_assert(K % 2 == 0, "K must be even");
  float4 wa[4], wb[4];
#pragma unroll
  for (int r = 0; r < 2; r++) {
    wa[2 * r]     = ld4(Wd + r * LD);
    wa[2 * r + 1] = ld4(Wd + r * LD + 4);
  }
#pragma unroll
  for (int c = 0; c < NC; c++) {
    if (c + 1 < NC) {
      float4 (&nxt)[4] = (c & 1) ? wa : wb;
#pragma unroll
      for (int r = 0; r < 2; r++) {
        nxt[2 * r]     = ld4(Wd + ((c + 1) * 2 + r) * LD);
        nxt[2 * r + 1] = ld4(Wd + ((c + 1) * 2 + r) * LD + 4);
      }
    }
    const float4 (&cur)[4] = (c & 1) ? wb : wa;
#pragma unroll
    for (int r = 0; r < 2; r++) fma8(h[c * 2 + r], cur[2 * r], cur[2 * r + 1], a);
  }
}

// Streaming-h variant: h[k] = hp[k*GPB]*scale read from LDS inside the loop.
template <int K, int LD>
__device__ __forceinline__ void gemm8s(const float* hp, float scale,
                                       const float* Wd, float (&a)[8]) {
  constexpr int NC = K / 2;
  static_assert(K % 2 == 0, "K must be even");
  float4 wa[4], wb[4];
  float h0 = hp[0] * scale, h1 = hp[GPB] * scale;
#pragma unroll
  for (int r = 0; r < 2; r++) {
    wa[2 * r]     = ld4(Wd + r * LD);
    wa[2 * r + 1] = ld4(Wd + r * LD + 4);
  }
#pragma unroll
  for (int c = 0; c < NC; c++) {
    const float hc0 = h0, hc1 = h1;
    if (c + 1 < NC) {
      h0 = hp[(2 * c + 2) * GPB] * scale;
      h1 = hp[(2 * c + 3) * GPB] * scale;
      float4 (&nxt)[4] = (c & 1) ? wa : wb;
#pragma unroll
      for (int r = 0; r < 2; r++) {
        nxt[2 * r]     = ld4(Wd + ((c + 1) * 2 + r) * LD);
        nxt[2 * r + 1] = ld4(Wd + ((c + 1) * 2 + r) * LD + 4);
      }
    }
    const float4 (&cur)[4] = (c & 1) ? wb : wa;
    fma8(hc0, cur[0], cur[1], a);
    fma8(hc1, cur[2], cur[3], a);
  }
}

__device__ __forceinline__ void bias8(const float* b, float (&a)[8]) {
  float4 b0 = ld4(b), b1 = ld4(b + 4);
  a[0] = b0.x; a[1] = b0.y; a[2] = b0.z; a[3] = b0.w;
  a[4] = b1.x; a[5] = b1.y; a[6] = b1.z; a[7] = b1.w;
}

__device__ __forceinline__ void bnsig8(const float* gam, const float* bet, float (&a)[8]) {
  float4 g0 = ld4(gam), g1 = ld4(gam + 4), b0 = ld4(bet), b1 = ld4(bet + 4);
  a[0] = sigm(fmaf(g0.x * INVC, a[0], b0.x));
  a[1] = sigm(fmaf(g0.y * INVC, a[1], b0.y));
  a[2] = sigm(fmaf(g0.z * INVC, a[2], b0.z));
  a[3] = sigm(fmaf(g0.w * INVC, a[3], b0.w));
  a[4] = sigm(fmaf(g1.x * INVC, a[4], b1.x));
  a[5] = sigm(fmaf(g1.y * INVC, a[5], b1.y));
  a[6] = sigm(fmaf(g1.z * INVC, a[6], b1.z));
  a[7] = sigm(fmaf(g1.w * INVC, a[7], b1.w));
}

// own 8 values + partner's 8 -> canonical 16-vector (dims 0..15)
__device__ __forceinline__ void pairfull(const float (&m)[8], int par, float (&o)[16]) {
#pragma unroll
  for (int j = 0; j < 8; j++) {
    const float sw = dpp_xor1(m[j]);
    o[j]     = par ? sw : m[j];
    o[8 + j] = par ? m[j] : sw;
  }
}

// 2 lanes per graph, 32 graphs per 1-wave block. LDS xs[176][32] = 22528 B.
// R14 experiment: __launch_bounds__(64,1) [= waves/EU floor 1, which empirically
// co-occurs with a 4-workgroup/CU residency ceiling across R3..R13] is replaced
// with explicit amdgpu_waves_per_eu(2,2): allocator budgets VGPR = pool/2
// (fits our ~252 if pool is 512/SIMD) and min=max prevents the R6 failure
// (floor=2 with no max -> allocator chased 4 waves -> 128-VGPR cap -> spill).
__global__ __launch_bounds__(NT)
__attribute__((amdgpu_waves_per_eu(2, 2)))
void gnn_kernel(P pp) {
  const int t = threadIdx.x;
  const int col = t >> 1;
  const int par = t & 1;
  const int d0 = par * 8;
  const int g = blockIdx.x * GPB + col;

  __shared__ float xs[176][GPB];

  // ---- raw edge features -> LDS rows 160..175 (own half: 8 values per lane)
  {
    const float4* q = (const float4*)(pp.edge_feat + (size_t)g * 16 + d0);
    float4 v0 = q[0], v1 = q[1];
    xs[160 + d0 + 0][col] = v0.x; xs[160 + d0 + 1][col] = v0.y;
    xs[160 + d0 + 2][col] = v0.z; xs[160 + d0 + 3][col] = v0.w;
    xs[160 + d0 + 4][col] = v1.x; xs[160 + d0 + 5][col] = v1.y;
    xs[160 + d0 + 6][col] = v1.z; xs[160 + d0 + 7][col] = v1.w;
  }

  // ---- node encoder: x[n][own 8 dims] -> LDS
#pragma unroll 1
  for (int n = 0; n < 5; n++) {
    float nfv[7];
#pragma unroll
    for (int k = 0; k < 7; k++) nfv[k] = pp.node_feat[(size_t)g * 35 + n * 7 + k];
    float a[8];
    bias8(pp.b_ne + d0, a);
#pragma unroll
    for (int k = 0; k < 7; k++) {
      const float* w = pp.W_ne + k * 16 + d0;
      fma8(nfv[k], ld4(w), ld4(w + 4), a);
    }
    const float gn = pp.g_ne[n] * INVC, bn = pp.be_ne[n];
#pragma unroll
    for (int j = 0; j < 8; j++) xs[n * 16 + d0 + j][col] = fmaf(gn, a[j], bn);
  }

  // ---- L message-passing layers
#pragma unroll 1
  for (int l = 0; l < 4; l++) {
    const float* mW1 = pp.msg_W1 + l * 576;
    const float* mb1 = pp.msg_b1 + l * 16;
    const float* mW2 = pp.msg_W2 + l * 256;
    const float* mb2 = pp.msg_b2 + l * 16;
    const float* uW1 = pp.upd_W1 + l * 512;
    const float* ub1 = pp.upd_b1 + l * 16;
    const float* uW2 = pp.upd_W2 + l * 256;
    const float* ub2 = pp.upd_b2 + l * 16;

    // zero my agg half
#pragma unroll
    for (int n = 0; n < 5; n++)
#pragma unroll
      for (int j = 0; j < 8; j++) xs[80 + n * 16 + d0 + j][col] = 0.f;

    // ---- phase A: per-edge messages
#pragma unroll 1
    for (int e = 0; e < 8; e++) {
      const int se = __builtin_amdgcn_readfirstlane(pp.ei[e]);
      const int de = __builtin_amdgcn_readfirstlane(pp.ei[8 + e]);

      const float e0 = xs[160 + 2 * e][col];
      const float e1 = xs[161 + 2 * e][col];

      float a[8];
      bias8(mb1 + d0, a);
      gemm8s<16, 16>(&xs[de * 16][col], 1.0f, mW1 + d0, a);
      gemm8s<16, 16>(&xs[se * 16][col], 1.0f, mW1 + 256 + d0, a);
      float ea4[4];
#pragma unroll
      for (int j = 0; j < 4; j++)
        ea4[j] = fmaf(e0, pp.W_ee[j], fmaf(e1, pp.W_ee[4 + j], pp.b_ee[j]));
      gemm8<4, 16>(mW1 + 512 + d0, ea4, a);

      float m1m[8];
#pragma unroll
      for (int j = 0; j < 8; j++) m1m[j] = sigm(a[j]);
      float m1all[16];
      pairfull(m1m, par, m1all);

      bias8(mb2 + d0, a);
      gemm8<16, 16>(mW2 + d0, m1all, a);
#pragma unroll
      for (int j = 0; j < 8; j++) xs[80 + de * 16 + d0 + j][col] += sigm(a[j]);
    }

    // ---- phase B: per-node update
#pragma unroll 1
    for (int n = 0; n < 5; n++) {
      int c = 0;
#pragma unroll
      for (int e = 0; e < 8; e++)
        c += (__builtin_amdgcn_readfirstlane(pp.ei[8 + e]) == n) ? 1 : 0;
      const float dr = 1.0f / (float)(c > 1 ? c : 1);

      float xm[8];
#pragma unroll
      for (int j = 0; j < 8; j++) xm[j] = xs[n * 16 + d0 + j][col];

      float a[8];
      bias8(ub1 + d0, a);
      gemm8s<16, 16>(&xs[n * 16][col], 1.0f, uW1 + d0, a);
      gemm8s<16, 16>(&xs[80 + n * 16][col], dr, uW1 + 256 + d0, a);

      const float G1 = pp.upd_g1[l * 5 + n] * INVC, B1 = pp.upd_be1[l * 5 + n];
      float u1m[8];
#pragma unroll
      for (int j = 0; j < 8; j++) u1m[j] = sigm(fmaf(G1, a[j], B1));
      float u1all[16];
      pairfull(u1m, par, u1all);

      bias8(ub2 + d0, a);
      gemm8<16, 16>(uW2 + d0, u1all, a);
      const float G2 = pp.upd_g2[l * 5 + n] * INVC, B2 = pp.upd_be2[l * 5 + n];
#pragma unroll
      for (int j = 0; j < 8; j++)
        xs[n * 16 + d0 + j][col] = xm[j] + sigm(fmaf(G2, a[j], B2));
    }
  }

  // ---- pooling -> rows 80..95
  {
    float a[8];
    bias8(pp.bp + d0, a);
#pragma unroll 1
    for (int nb = 0; nb < 5; nb++)
      gemm8s<16, 16>(&xs[nb * 16][col], 1.0f, pp.Wp + nb * 256 + d0, a);
    bnsig8(pp.gp + d0, pp.bep + d0, a);
#pragma unroll
    for (int j = 0; j < 8; j++) xs[80 + d0 + j][col] = a[j];
  }

  // ---- MLP head (lane owns 32 of 64 outputs: grp*16 + d0 + j)
  // mlp1: rows 80..95 -> rows 0..63
#pragma unroll 1
  for (int grp = 0; grp < 4; grp++) {
    const int ob = grp * 16 + d0;
    float a[8];
    bias8(pp.mb1 + ob, a);
    gemm8s<16, 64>(&xs[80][col], 1.0f, pp.mW1 + ob, a);
    bnsig8(pp.mg1 + ob, pp.mbe1 + ob, a);
#pragma unroll
    for (int j = 0; j < 8; j++) xs[ob + j][col] = a[j];
  }
  // mlp2: rows 0..63 -> rows 80..143
  {
    float acc[4][8];
#pragma unroll
    for (int grp = 0; grp < 4; grp++) bias8(pp.mb2 + grp * 16 + d0, acc[grp]);
#pragma unroll 1
    for (int kb = 0; kb < 4; kb++) {
#pragma unroll
      for (int grp = 0; grp < 4; grp++)
        gemm8s<16, 64>(&xs[kb * 16][col], 1.0f,
                       pp.mW2 + (kb * 16) * 64 + grp * 16 + d0, acc[grp]);
    }
#pragma unroll
    for (int grp = 0; grp < 4; grp++) {
      const int ob = grp * 16 + d0;
      bnsig8(pp.mg2 + ob, pp.mbe2 + ob, acc[grp]);
#pragma unroll
      for (int j = 0; j < 8; j++) xs[80 + ob + j][col] = acc[grp][j];
    }
  }
  // mlp3: rows 80..143 -> rows 0..63
  {
    float acc[4][8];
#pragma unroll
    for (int grp = 0; grp < 4; grp++) bias8(pp.mb3 + grp * 16 + d0, acc[grp]);
#pragma unroll 1
    for (int kb = 0; kb < 4; kb++) {
#pragma unroll
      for (int grp = 0; grp < 4; grp++)
        gemm8s<16, 64>(&xs[80 + kb * 16][col], 1.0f,
                       pp.mW3 + (kb * 16) * 64 + grp * 16 + d0, acc[grp]);
    }
#pragma unroll
    for (int grp = 0; grp < 4; grp++) {
      const int ob = grp * 16 + d0;
      bnsig8(pp.mg3 + ob, pp.mbe3 + ob, acc[grp]);
#pragma unroll
      for (int j = 0; j < 8; j++) xs[ob + j][col] = acc[grp][j];
    }
  }
  // mlp4: rows 0..63 -> out (pair-split dot + DPP combine)
  {
    const float* w4 = pp.mW4 + par * 32;
    float s0 = 0.f, s1 = 0.f, s2 = 0.f, s3 = 0.f;
#pragma unroll
    for (int r = 0; r < 8; r++) {
      float4 wv = ld4(w4 + r * 4);
      s0 = fmaf(xs[par * 32 + r * 4 + 0][col], wv.x, s0);
      s1 = fmaf(xs[par * 32 + r * 4 + 1][col], wv.y, s1);
      s2 = fmaf(xs[par * 32 + r * 4 + 2][col], wv.z, s2);
      s3 = fmaf(xs[par * 32 + r * 4 + 3][col], wv.w, s3);
    }
    float s = (s0 + s1) + (s2 + s3);
    s += dpp_xor1(s);
    s += pp.mb4[0];
    if (par == 0) pp.out[g] = s;
  }
}

extern "C" void kernel_launch(void* const* d_in, const int* in_sizes, int n_in,
                              void* d_out, int out_size, void* d_ws, size_t ws_size,
                              hipStream_t stream) {
  P p;
  p.node_feat = (const float*)d_in[0];
  p.edge_feat = (const float*)d_in[1];
  p.ei        = (const int*)d_in[2];
  p.W_ne  = (const float*)d_in[3];  p.b_ne  = (const float*)d_in[4];
  p.g_ne  = (const float*)d_in[5];  p.be_ne = (const float*)d_in[6];
  p.W_ee  = (const float*)d_in[7];  p.b_ee  = (const float*)d_in[8];
  p.msg_W1 = (const float*)d_in[9];  p.msg_b1 = (const float*)d_in[10];
  p.msg_W2 = (const float*)d_in[11]; p.msg_b2 = (const float*)d_in[12];
  p.upd_W1 = (const float*)d_in[13]; p.upd_b1 = (const float*)d_in[14];
  p.upd_g1 = (const float*)d_in[15]; p.upd_be1 = (const float*)d_in[16];
  p.upd_W2 = (const float*)d_in[17]; p.upd_b2 = (const float*)d_in[18];
  p.upd_g2 = (const float*)d_in[19]; p.upd_be2 = (const float*)d_in[20];
  p.Wp  = (const float*)d_in[21]; p.bp  = (const float*)d_in[22];
  p.gp  = (const float*)d_in[23]; p.bep = (const float*)d_in[24];
  p.mW1 = (const float*)d_in[25]; p.mb1 = (const float*)d_in[26];
  p.mg1 = (const float*)d_in[27]; p.mbe1 = (const float*)d_in[28];
  p.mW2 = (const float*)d_in[29]; p.mb2 = (const float*)d_in[30];
  p.mg2 = (const float*)d_in[31]; p.mbe2 = (const float*)d_in[32];
  p.mW3 = (const float*)d_in[33]; p.mb3 = (const float*)d_in[34];
  p.mg3 = (const float*)d_in[35]; p.mbe3 = (const float*)d_in[36];
  p.mW4 = (const float*)d_in[37]; p.mb4 = (const float*)d_in[38];
  p.out = (float*)d_out;

  hipLaunchKernelGGL(gnn_kernel, dim3(NB / GPB), dim3(NT), 0, stream, p);
}

// Round 15
// 933.531 us; speedup vs baseline: 4.7316x; 4.7316x over previous
//
#include <hip/hip_runtime.h>

#define NT 64
#define GPB 64   // graphs per block (2 per lane-pair)
#define NB 262144

struct P {
  const float* node_feat; const float* edge_feat; const int* ei;
  const float* W_ne; const float* b_ne; const float* g_ne; const float* be_ne;
  const float* W_ee; const float* b_ee;
  const float* msg_W1; const float* msg_b1; const float* msg_W2; const float* msg_b2;
  const float* upd_W1; const float* upd_b1; const float* upd_g1; const float* upd_be1;
  const float* upd_W2; const float* upd_b2; const float* upd_g2; const float* upd_be2;
  const float* Wp; const float* bp; const float* gp; const float* bep;
  const float* mW1; const float* mb1; const float* mg1; const float* mbe1;
  const float* mW2; const float* mb2; const float* mg2; const float* mbe2;
  const float* mW3; const float* mb3; const float* mg3; const float* mbe3;
  const float* mW4; const float* mb4;
  float* out;
};

// 1/sqrt(1+1e-5)
#define INVC 0.9999950000374997f

__device__ __forceinline__ float sigm(float x) {
  return __builtin_amdgcn_rcpf(1.0f + __expf(-x));
}

// exchange within lane pairs (2p <-> 2p+1): quad_perm [1,0,3,2] = 0xB1 (R5-verified)
__device__ __forceinline__ float dpp_xor1(float v) {
  return __builtin_bit_cast(float, __builtin_amdgcn_update_dpp(
      0, __builtin_bit_cast(int, v), 0xB1, 0xF, 0xF, false));
}

__device__ __forceinline__ float4 ld4(const float* p_) { return *(const float4*)p_; }

__device__ __forceinline__ void fma8(float hv, const float4 w0, const float4 w1,
                                     float (&a)[8]) {
  a[0] = fmaf(hv, w0.x, a[0]); a[1] = fmaf(hv, w0.y, a[1]);
  a[2] = fmaf(hv, w0.z, a[2]); a[3] = fmaf(hv, w0.w, a[3]);
  a[4] = fmaf(hv, w1.x, a[4]); a[5] = fmaf(hv, w1.y, a[5]);
  a[6] = fmaf(hv, w1.z, a[6]); a[7] = fmaf(hv, w1.w, a[7]);
}

// R15 core: one weight chunk, TWO graphs' FMAs -> 64-cyc compute window per
// chunk (vs 32 in R13) against the same ~120-200cyc load latency, at only
// +8 acc +16 h registers (no extra staging). 2-row double-buffered chunks.
template <int K, int LD>
__device__ __forceinline__ void gemm8x2(const float* Wd,
                                        const float (&hA)[K], const float (&hB)[K],
                                        float (&aA)[8], float (&aB)[8]) {
  constexpr int NC = K / 2;
  static_assert(K % 2 == 0, "K must be even");
  float4 wa[4], wb[4];
#pragma unroll
  for (int r = 0; r < 2; r++) {
    wa[2 * r]     = ld4(Wd + r * LD);
    wa[2 * r + 1] = ld4(Wd + r * LD + 4);
  }
#pragma unroll
  for (int c = 0; c < NC; c++) {
    if (c + 1 < NC) {
      float4 (&nxt)[4] = (c & 1) ? wa : wb;
#pragma unroll
      for (int r = 0; r < 2; r++) {
        nxt[2 * r]     = ld4(Wd + ((c + 1) * 2 + r) * LD);
        nxt[2 * r + 1] = ld4(Wd + ((c + 1) * 2 + r) * LD + 4);
      }
    }
    const float4 (&cur)[4] = (c & 1) ? wb : wa;
    fma8(hA[2 * c],     cur[0], cur[1], aA);
    fma8(hB[2 * c],     cur[0], cur[1], aB);
    fma8(hA[2 * c + 1], cur[2], cur[3], aA);
    fma8(hB[2 * c + 1], cur[2], cur[3], aB);
  }
}

__device__ __forceinline__ void bias8(const float* b, float (&a)[8]) {
  float4 b0 = ld4(b), b1 = ld4(b + 4);
  a[0] = b0.x; a[1] = b0.y; a[2] = b0.z; a[3] = b0.w;
  a[4] = b1.x; a[5] = b1.y; a[6] = b1.z; a[7] = b1.w;
}

__device__ __forceinline__ void bnsig8(const float* gam, const float* bet, float (&a)[8]) {
  float4 g0 = ld4(gam), g1 = ld4(gam + 4), b0 = ld4(bet), b1 = ld4(bet + 4);
  a[0] = sigm(fmaf(g0.x * INVC, a[0], b0.x));
  a[1] = sigm(fmaf(g0.y * INVC, a[1], b0.y));
  a[2] = sigm(fmaf(g0.z * INVC, a[2], b0.z));
  a[3] = sigm(fmaf(g0.w * INVC, a[3], b0.w));
  a[4] = sigm(fmaf(g1.x * INVC, a[4], b1.x));
  a[5] = sigm(fmaf(g1.y * INVC, a[5], b1.y));
  a[6] = sigm(fmaf(g1.z * INVC, a[6], b1.z));
  a[7] = sigm(fmaf(g1.w * INVC, a[7], b1.w));
}

// own 8 values + partner's 8 -> canonical 16-vector (dims 0..15)
__device__ __forceinline__ void pairfull(const float (&m)[8], int par, float (&o)[16]) {
#pragma unroll
  for (int j = 0; j < 8; j++) {
    const float sw = dpp_xor1(m[j]);
    o[j]     = par ? sw : m[j];
    o[8 + j] = par ? m[j] : sw;
  }
}

// batch 16 consecutive rows of one column into registers (latency paid once)
__device__ __forceinline__ void loadh16(const float* base, float (&h)[16]) {
#pragma unroll
  for (int k = 0; k < 16; k++) h[k] = base[k * GPB];
}
__device__ __forceinline__ void loadh16s(const float* base, float s, float (&h)[16]) {
#pragma unroll
  for (int k = 0; k < 16; k++) h[k] = base[k * GPB] * s;
}

// 2 lanes per graph x 2 graphs per lane-pair; 64 graphs per 1-wave block.
// LDS xs[160][64] = 40960 B: rows 0..79 x[n][d], rows 80..159 agg / MLP ping-pong.
// Columns: graph gA=blk*64+p -> col p; gB=gA+32 -> col 32+p. Banks: col%32 ->
// conflict-free per instruction (2 lanes/bank broadcast or 2-way = free, m136).
// Zero barriers. __launch_bounds__(64,1): only non-spilling config (R3..R14).
__global__ __launch_bounds__(NT, 1) void gnn_kernel(P pp) {
  const int t = threadIdx.x;
  const int p = t >> 1;
  const int par = t & 1;
  const int d0 = par * 8;
  const int gA = blockIdx.x * GPB + p;
  const int gB = gA + 32;
  const int cA = p;
  const int cB = 32 + p;

  __shared__ float xs[160][GPB];

  const float* efA = pp.edge_feat + (size_t)gA * 16;
  const float* efB = pp.edge_feat + (size_t)gB * 16;

  // ---- node encoder for both graphs
#pragma unroll 1
  for (int gi = 0; gi < 2; gi++) {
    const float* nf = pp.node_feat + (size_t)(gi ? gB : gA) * 35;
    const int c = gi ? cB : cA;
#pragma unroll 1
    for (int n = 0; n < 5; n++) {
      float nfv[7];
#pragma unroll
      for (int k = 0; k < 7; k++) nfv[k] = nf[n * 7 + k];
      float a[8];
      bias8(pp.b_ne + d0, a);
#pragma unroll
      for (int k = 0; k < 7; k++) {
        const float* w = pp.W_ne + k * 16 + d0;
        fma8(nfv[k], ld4(w), ld4(w + 4), a);
      }
      const float gn = pp.g_ne[n] * INVC, bn = pp.be_ne[n];
#pragma unroll
      for (int j = 0; j < 8; j++) xs[n * 16 + d0 + j][c] = fmaf(gn, a[j], bn);
    }
  }

  // ---- L message-passing layers
#pragma unroll 1
  for (int l = 0; l < 4; l++) {
    const float* mW1 = pp.msg_W1 + l * 576;
    const float* mb1 = pp.msg_b1 + l * 16;
    const float* mW2 = pp.msg_W2 + l * 256;
    const float* mb2 = pp.msg_b2 + l * 16;
    const float* uW1 = pp.upd_W1 + l * 512;
    const float* ub1 = pp.upd_b1 + l * 16;
    const float* uW2 = pp.upd_W2 + l * 256;
    const float* ub2 = pp.upd_b2 + l * 16;

    // zero agg halves (both columns)
#pragma unroll
    for (int n = 0; n < 5; n++)
#pragma unroll
      for (int j = 0; j < 8; j++) {
        xs[80 + n * 16 + d0 + j][cA] = 0.f;
        xs[80 + n * 16 + d0 + j][cB] = 0.f;
      }

    // ---- phase A: per-edge messages (weights shared across both graphs)
#pragma unroll 1
    for (int e = 0; e < 8; e++) {
      const int se = __builtin_amdgcn_readfirstlane(pp.ei[e]);
      const int de = __builtin_amdgcn_readfirstlane(pp.ei[8 + e]);

      // edge-feature scalars (L2/L3-hot; issued early, hidden under gemms)
      const float e0A = efA[2 * e], e1A = efA[2 * e + 1];
      const float e0B = efB[2 * e], e1B = efB[2 * e + 1];

      float aA[8], aB[8];
      bias8(mb1 + d0, aA);
#pragma unroll
      for (int j = 0; j < 8; j++) aB[j] = aA[j];

      {
        float hA[16], hB[16];
        loadh16(&xs[de * 16][cA], hA);
        loadh16(&xs[de * 16][cB], hB);
        gemm8x2<16, 16>(mW1 + d0, hA, hB, aA, aB);
        loadh16(&xs[se * 16][cA], hA);
        loadh16(&xs[se * 16][cB], hB);
        gemm8x2<16, 16>(mW1 + 256 + d0, hA, hB, aA, aB);
      }
      {
        float eaA[4], eaB[4];
#pragma unroll
        for (int j = 0; j < 4; j++) {
          const float we0 = pp.W_ee[j], we1 = pp.W_ee[4 + j], be = pp.b_ee[j];
          eaA[j] = fmaf(e0A, we0, fmaf(e1A, we1, be));
          eaB[j] = fmaf(e0B, we0, fmaf(e1B, we1, be));
        }
        gemm8x2<4, 16>(mW1 + 512 + d0, eaA, eaB, aA, aB);
      }

      float m1A[16], m1B[16];
      {
        float mm[8];
#pragma unroll
        for (int j = 0; j < 8; j++) mm[j] = sigm(aA[j]);
        pairfull(mm, par, m1A);
#pragma unroll
        for (int j = 0; j < 8; j++) mm[j] = sigm(aB[j]);
        pairfull(mm, par, m1B);
      }

      bias8(mb2 + d0, aA);
#pragma unroll
      for (int j = 0; j < 8; j++) aB[j] = aA[j];
      gemm8x2<16, 16>(mW2 + d0, m1A, m1B, aA, aB);
#pragma unroll
      for (int j = 0; j < 8; j++) {
        xs[80 + de * 16 + d0 + j][cA] += sigm(aA[j]);
        xs[80 + de * 16 + d0 + j][cB] += sigm(aB[j]);
      }
    }

    // ---- phase B: per-node update (both graphs)
#pragma unroll 1
    for (int n = 0; n < 5; n++) {
      int cnt = 0;
#pragma unroll
      for (int e = 0; e < 8; e++)
        cnt += (__builtin_amdgcn_readfirstlane(pp.ei[8 + e]) == n) ? 1 : 0;
      const float dr = 1.0f / (float)(cnt > 1 ? cnt : 1);

      float aA[8], aB[8];
      bias8(ub1 + d0, aA);
#pragma unroll
      for (int j = 0; j < 8; j++) aB[j] = aA[j];
      {
        float hA[16], hB[16];
        loadh16(&xs[n * 16][cA], hA);
        loadh16(&xs[n * 16][cB], hB);
        gemm8x2<16, 16>(uW1 + d0, hA, hB, aA, aB);
        loadh16s(&xs[80 + n * 16][cA], dr, hA);
        loadh16s(&xs[80 + n * 16][cB], dr, hB);
        gemm8x2<16, 16>(uW1 + 256 + d0, hA, hB, aA, aB);
      }

      const float G1 = pp.upd_g1[l * 5 + n] * INVC, B1 = pp.upd_be1[l * 5 + n];
      float u1A[16], u1B[16];
      {
        float mm[8];
#pragma unroll
        for (int j = 0; j < 8; j++) mm[j] = sigm(fmaf(G1, aA[j], B1));
        pairfull(mm, par, u1A);
#pragma unroll
        for (int j = 0; j < 8; j++) mm[j] = sigm(fmaf(G1, aB[j], B1));
        pairfull(mm, par, u1B);
      }

      bias8(ub2 + d0, aA);
#pragma unroll
      for (int j = 0; j < 8; j++) aB[j] = aA[j];
      gemm8x2<16, 16>(uW2 + d0, u1A, u1B, aA, aB);
      const float G2 = pp.upd_g2[l * 5 + n] * INVC, B2 = pp.upd_be2[l * 5 + n];
#pragma unroll
      for (int j = 0; j < 8; j++) {
        xs[n * 16 + d0 + j][cA] += sigm(fmaf(G2, aA[j], B2));
        xs[n * 16 + d0 + j][cB] += sigm(fmaf(G2, aB[j], B2));
      }
    }
  }

  // ---- pooling -> rows 80..95 (both columns)
  {
    float aA[8], aB[8];
    bias8(pp.bp + d0, aA);
#pragma unroll
    for (int j = 0; j < 8; j++) aB[j] = aA[j];
#pragma unroll 1
    for (int nb = 0; nb < 5; nb++) {
      float hA[16], hB[16];
      loadh16(&xs[nb * 16][cA], hA);
      loadh16(&xs[nb * 16][cB], hB);
      gemm8x2<16, 16>(pp.Wp + nb * 256 + d0, hA, hB, aA, aB);
    }
    bnsig8(pp.gp + d0, pp.bep + d0, aA);
    bnsig8(pp.gp + d0, pp.bep + d0, aB);
#pragma unroll
    for (int j = 0; j < 8; j++) {
      xs[80 + d0 + j][cA] = aA[j];
      xs[80 + d0 + j][cB] = aB[j];
    }
  }

  // ---- MLP head (lane owns 32 of 64 outputs per graph: grp*16 + d0 + j)
  // mlp1: rows 80..95 -> rows 0..63
  {
    float hA[16], hB[16];
    loadh16(&xs[80][cA], hA);
    loadh16(&xs[80][cB], hB);
#pragma unroll 1
    for (int grp = 0; grp < 4; grp++) {
      const int ob = grp * 16 + d0;
      float aA[8], aB[8];
      bias8(pp.mb1 + ob, aA);
#pragma unroll
      for (int j = 0; j < 8; j++) aB[j] = aA[j];
      gemm8x2<16, 64>(pp.mW1 + ob, hA, hB, aA, aB);
      bnsig8(pp.mg1 + ob, pp.mbe1 + ob, aA);
      bnsig8(pp.mg1 + ob, pp.mbe1 + ob, aB);
#pragma unroll
      for (int j = 0; j < 8; j++) {
        xs[ob + j][cA] = aA[j];
        xs[ob + j][cB] = aB[j];
      }
    }
  }
  // mlp2: rows 0..63 -> rows 80..143
  {
    float accA[4][8], accB[4][8];
#pragma unroll
    for (int grp = 0; grp < 4; grp++) {
      bias8(pp.mb2 + grp * 16 + d0, accA[grp]);
#pragma unroll
      for (int j = 0; j < 8; j++) accB[grp][j] = accA[grp][j];
    }
#pragma unroll 1
    for (int kb = 0; kb < 4; kb++) {
      float hA[16], hB[16];
      loadh16(&xs[kb * 16][cA], hA);
      loadh16(&xs[kb * 16][cB], hB);
#pragma unroll
      for (int grp = 0; grp < 4; grp++)
        gemm8x2<16, 64>(pp.mW2 + (kb * 16) * 64 + grp * 16 + d0, hA, hB,
                        accA[grp], accB[grp]);
    }
#pragma unroll
    for (int grp = 0; grp < 4; grp++) {
      const int ob = grp * 16 + d0;
      bnsig8(pp.mg2 + ob, pp.mbe2 + ob, accA[grp]);
      bnsig8(pp.mg2 + ob, pp.mbe2 + ob, accB[grp]);
#pragma unroll
      for (int j = 0; j < 8; j++) {
        xs[80 + ob + j][cA] = accA[grp][j];
        xs[80 + ob + j][cB] = accB[grp][j];
      }
    }
  }
  // mlp3: rows 80..143 -> rows 0..63
  {
    float accA[4][8], accB[4][8];
#pragma unroll
    for (int grp = 0; grp < 4; grp++) {
      bias8(pp.mb3 + grp * 16 + d0, accA[grp]);
#pragma unroll
      for (int j = 0; j < 8; j++) accB[grp][j] = accA[grp][j];
    }
#pragma unroll 1
    for (int kb = 0; kb < 4; kb++) {
      float hA[16], hB[16];
      loadh16(&xs[80 + kb * 16][cA], hA);
      loadh16(&xs[80 + kb * 16][cB], hB);
#pragma unroll
      for (int grp = 0; grp < 4; grp++)
        gemm8x2<16, 64>(pp.mW3 + (kb * 16) * 64 + grp * 16 + d0, hA, hB,
                        accA[grp], accB[grp]);
    }
#pragma unroll
    for (int grp = 0; grp < 4; grp++) {
      const int ob = grp * 16 + d0;
      bnsig8(pp.mg3 + ob, pp.mbe3 + ob, accA[grp]);
      bnsig8(pp.mg3 + ob, pp.mbe3 + ob, accB[grp]);
#pragma unroll
      for (int j = 0; j < 8; j++) {
        xs[ob + j][cA] = accA[grp][j];
        xs[ob + j][cB] = accB[grp][j];
      }
    }
  }
  // mlp4: rows 0..63 -> out (pair-split dot + DPP combine, both graphs)
  {
    const float* w4 = pp.mW4 + par * 32;
    float4 wv[8];
#pragma unroll
    for (int r = 0; r < 8; r++) wv[r] = ld4(w4 + r * 4);

    float sA0 = 0.f, sA1 = 0.f, sA2 = 0.f, sA3 = 0.f;
    float sB0 = 0.f, sB1 = 0.f, sB2 = 0.f, sB3 = 0.f;
#pragma unroll
    for (int r = 0; r < 8; r++) {
      const int rb = par * 32 + r * 4;
      sA0 = fmaf(xs[rb + 0][cA], wv[r].x, sA0);
      sA1 = fmaf(xs[rb + 1][cA], wv[r].y, sA1);
      sA2 = fmaf(xs[rb + 2][cA], wv[r].z, sA2);
      sA3 = fmaf(xs[rb + 3][cA], wv[r].w, sA3);
      sB0 = fmaf(xs[rb + 0][cB], wv[r].x, sB0);
      sB1 = fmaf(xs[rb + 1][cB], wv[r].y, sB1);
      sB2 = fmaf(xs[rb + 2][cB], wv[r].z, sB2);
      sB3 = fmaf(xs[rb + 3][cB], wv[r].w, sB3);
    }
    float sA = (sA0 + sA1) + (sA2 + sA3);
    float sB = (sB0 + sB1) + (sB2 + sB3);
    sA += dpp_xor1(sA);
    sB += dpp_xor1(sB);
    const float b4 = pp.mb4[0];
    if (par == 0) {
      pp.out[gA] = sA + b4;
      pp.out[gB] = sB + b4;
    }
  }
}

extern "C" void kernel_launch(void* const* d_in, const int* in_sizes, int n_in,
                              void* d_out, int out_size, void* d_ws, size_t ws_size,
                              hipStream_t stream) {
  P p;
  p.node_feat = (const float*)d_in[0];
  p.edge_feat = (const float*)d_in[1];
  p.ei        = (const int*)d_in[2];
  p.W_ne  = (const float*)d_in[3];  p.b_ne  = (const float*)d_in[4];
  p.g_ne  = (const float*)d_in[5];  p.be_ne = (const float*)d_in[6];
  p.W_ee  = (const float*)d_in[7];  p.b_ee  = (const float*)d_in[8];
  p.msg_W1 = (const float*)d_in[9];  p.msg_b1 = (const float*)d_in[10];
  p.msg_W2 = (const float*)d_in[11]; p.msg_b2 = (const float*)d_in[12];
  p.upd_W1 = (const float*)d_in[13]; p.upd_b1 = (const float*)d_in[14];
  p.upd_g1 = (const float*)d_in[15]; p.upd_be1 = (const float*)d_in[16];
  p.upd_W2 = (const float*)d_in[17]; p.upd_b2 = (const float*)d_in[18];
  p.upd_g2 = (const float*)d_in[19]; p.upd_be2 = (const float*)d_in[20];
  p.Wp  = (const float*)d_in[21]; p.bp  = (const float*)d_in[22];
  p.gp  = (const float*)d_in[23]; p.bep = (const float*)d_in[24];
  p.mW1 = (const float*)d_in[25]; p.mb1 = (const float*)d_in[26];
  p.mg1 = (const float*)d_in[27]; p.mbe1 = (const float*)d_in[28];
  p.mW2 = (const float*)d_in[29]; p.mb2 = (const float*)d_in[30];
  p.mg2 = (const float*)d_in[31]; p.mbe2 = (const float*)d_in[32];
  p.mW3 = (const float*)d_in[33]; p.mb3 = (const float*)d_in[34];
  p.mg3 = (const float*)d_in[35]; p.mbe3 = (const float*)d_in[36];
  p.mW4 = (const float*)d_in[37]; p.mb4 = (const float*)d_in[38];
  p.out = (float*)d_out;

  hipLaunchKernelGGL(gnn_kernel, dim3(NB / GPB), dim3(NT), 0, stream, p);
}

// Round 16
// 337.578 us; speedup vs baseline: 13.0846x; 2.7654x over previous
//
#include <hip/hip_runtime.h>

#define NT 256       // 4 waves/block
#define GPB 64       // graphs per block (16 per wave)
#define NB 262144
#define NCOL 66      // 64 graph columns + 2 pad (bank spread for A-reads)
#define ROWS 128
// 1/sqrt(1+1e-5)
#define INVC 0.9999950000374997f

typedef __attribute__((ext_vector_type(8))) short bf8;
typedef __attribute__((ext_vector_type(4))) float f4;

struct P {
  const float* node_feat; const float* edge_feat; const int* ei;
  const float* W_ne; const float* b_ne; const float* g_ne; const float* be_ne;
  const float* W_ee; const float* b_ee;
  const float* msg_W1; const float* msg_b1; const float* msg_W2; const float* msg_b2;
  const float* upd_W1; const float* upd_b1; const float* upd_g1; const float* upd_be1;
  const float* upd_W2; const float* upd_b2; const float* upd_g2; const float* upd_be2;
  const float* Wp; const float* bp; const float* gp; const float* bep;
  const float* mW1; const float* mb1; const float* mg1; const float* mbe1;
  const float* mW2; const float* mb2; const float* mg2; const float* mbe2;
  const float* mW3; const float* mb3; const float* mg3; const float* mbe3;
  const float* mW4; const float* mb4;
  float* out;
};

__device__ __forceinline__ float sigm(float x) {
  return __builtin_amdgcn_rcpf(1.0f + __expf(-x));
}

__device__ __forceinline__ float bff(short s) {
  return __builtin_bit_cast(float, ((unsigned)(unsigned short)s) << 16);
}

// split-bf16 fragment: value ≈ hi + lo (each bf16), products exact to ~2^-16
struct F2 { bf8 h, l; };

__device__ __forceinline__ F2 pack2(const float (&v)[8]) {
  F2 r;
#pragma unroll
  for (int i = 0; i < 8; i++) {
    short hi = (short)(__builtin_bit_cast(unsigned, v[i]) >> 16);  // truncate
    r.h[i] = hi;
    float res = v[i] - bff(hi);
    r.l[i] = (short)(__builtin_bit_cast(unsigned, res) >> 16);
  }
  return r;
}

// D += A*B with split operands (drop lo*lo, ~1e-5 rel)
__device__ __forceinline__ f4 mm(const F2& a, const F2& b, f4 c) {
  c = __builtin_amdgcn_mfma_f32_16x16x32_bf16(a.l, b.h, c, 0, 0, 0);
  c = __builtin_amdgcn_mfma_f32_16x16x32_bf16(a.h, b.l, c, 0, 0, 0);
  c = __builtin_amdgcn_mfma_f32_16x16x32_bf16(a.h, b.h, c, 0, 0, 0);
  return c;
}

// B-fragment from global weights W[k][n] (row-major, LD): k̂ = 8q+i, n fixed/lane
template <int KV>
__device__ __forceinline__ F2 packB(const float* W, int LD, int q, int n) {
  float v[8];
#pragma unroll
  for (int i = 0; i < 8; i++) {
    const int kq = 8 * q + i;
    v[i] = (kq < KV) ? W[kq * LD + n] : 0.f;
  }
  return pack2(v);
}

// A-fragment from LDS column xb = &xs[0][col]; per-lane row base (K=32 full)
__device__ __forceinline__ F2 packAr(const float* xb, int row0) {
  float v[8];
#pragma unroll
  for (int i = 0; i < 8; i++) v[i] = xb[(row0 + i) * NCOL];
  return pack2(v);
}
// K=16 variant (upper half zero): rows rowbase..rowbase+15
__device__ __forceinline__ F2 packA16(const float* xb, int rowbase, int q) {
  float v[8];
#pragma unroll
  for (int i = 0; i < 8; i++) {
    const int k = 8 * q + i;
    v[i] = (k < 16) ? xb[(rowbase + k) * NCOL] : 0.f;
  }
  return pack2(v);
}

// write D-frag to LDS [dim][graph]: row = dimbase + (lane&15), cols cD..cD+3
__device__ __forceinline__ void wrD(float* dst, f4 d) {
  *(float2*)dst = float2{d[0], d[1]};
  *(float2*)(dst + 2) = float2{d[2], d[3]};
}

__device__ __forceinline__ f4 splat4(float b) { return f4{b, b, b, b}; }

// 4 independent waves per block; wave w owns graph columns 16w..16w+15.
// LDS [dim-row][graph-col]: rows 0-79 x, 80-95 scratch (roundtrips), MLP uses
// 0-63 / 64-127 ping-pong. Zero barriers (no cross-wave column sharing).
__global__ __launch_bounds__(NT, 1) void gnn_kernel(P pp) {
  __shared__ float xs[ROWS][NCOL];

  const int t = threadIdx.x;
  const int w = t >> 6;
  const int l = t & 63;
  const int q = l >> 4;
  const int m16 = l & 15;
  const int col = w * 16 + m16;       // A-read / mlp4 column (graph gbase+m16)
  const int cD = w * 16 + 4 * q;      // D-frag column base (graphs gbase+4q+r)
  const int gbase = blockIdx.x * GPB + w * 16;

  const float* xb = &xs[0][col];
  const f4 z4 = {0.f, 0.f, 0.f, 0.f};

  // edge index -> SGPRs
  int se_[8], de_[8];
#pragma unroll
  for (int e = 0; e < 8; e++) {
    se_[e] = __builtin_amdgcn_readfirstlane(pp.ei[e]);
    de_[e] = __builtin_amdgcn_readfirstlane(pp.ei[8 + e]);
  }
  float dr_[5];
#pragma unroll
  for (int n = 0; n < 5; n++) {
    int c = 0;
#pragma unroll
    for (int e = 0; e < 8; e++) c += (de_[e] == n) ? 1 : 0;
    dr_[n] = 1.0f / (float)(c > 1 ? c : 1);
  }

  // ---------------- node encoder: 5 MFMA tiles, one shared B ----------------
  {
    F2 Bne = packB<7>(pp.W_ne, 16, q, m16);
#pragma unroll 1
    for (int n = 0; n < 5; n++) {
      float v[8];
#pragma unroll
      for (int i = 0; i < 8; i++) {
        const int k = 8 * q + i;
        v[i] = (k < 7) ? pp.node_feat[(size_t)(gbase + m16) * 35 + n * 7 + k] : 0.f;
      }
      F2 a = pack2(v);
      f4 d = mm(a, Bne, z4);
      const float gn = pp.g_ne[n] * INVC, bn = pp.be_ne[n];
      f4 o;
#pragma unroll
      for (int r = 0; r < 4; r++) o[r] = fmaf(gn, d[r], bn);
      wrD(&xs[n * 16 + m16][cD], o);
    }
  }

  // ---------------- L message-passing layers ----------------
#pragma unroll 1
  for (int l4 = 0; l4 < 4; l4++) {
    const float* mW1 = pp.msg_W1 + l4 * 576;
    F2 B1a = packB<32>(mW1, 16, q, m16);          // [hi|hj] rows 0-31
    F2 B1e = packB<4>(mW1 + 512, 16, q, m16);     // ea rows 32-35
    F2 B2  = packB<16>(pp.msg_W2 + l4 * 256, 16, q, m16);
    F2 BU1 = packB<32>(pp.upd_W1 + l4 * 512, 16, q, m16);
    F2 BU2 = packB<16>(pp.upd_W2 + l4 * 256, 16, q, m16);
    const float mb1n = pp.msg_b1[l4 * 16 + m16];
    const float mb2n = pp.msg_b2[l4 * 16 + m16];
    const float ub1n = pp.upd_b1[l4 * 16 + m16];
    const float ub2n = pp.upd_b2[l4 * 16 + m16];

    f4 agg[5];
#pragma unroll
    for (int n = 0; n < 5; n++) agg[n] = z4;

    // ---- phase A: per-edge messages ----
#pragma unroll 1
    for (int e = 0; e < 8; e++) {
      const int se = se_[e], de = de_[e];

      // ea A-frag (only lanes q==0, k<4 nonzero)
      float v[8] = {0.f, 0.f, 0.f, 0.f, 0.f, 0.f, 0.f, 0.f};
      if (q == 0) {
        const float* ef = pp.edge_feat + (size_t)(gbase + m16) * 16 + 2 * e;
        const float e0 = ef[0], e1 = ef[1];
#pragma unroll
        for (int j = 0; j < 4; j++)
          v[j] = fmaf(e0, pp.W_ee[j], fmaf(e1, pp.W_ee[4 + j], pp.b_ee[j]));
      }
      F2 aea = pack2(v);

      f4 c1 = splat4(mb1n);
      c1 = mm(aea, B1e, c1);
      const int rowH = (q < 2) ? de * 16 + 8 * q : se * 16 + 8 * (q - 2);
      F2 ah = packAr(xb, rowH);
      c1 = mm(ah, B1a, c1);
#pragma unroll
      for (int r = 0; r < 4; r++) c1[r] = sigm(c1[r]);
      wrD(&xs[80 + m16][cD], c1);           // roundtrip (D-layout -> A-layout)
      F2 am = packA16(xb, 80, q);

      f4 c2 = splat4(mb2n);
      c2 = mm(am, B2, c2);
#pragma unroll
      for (int r = 0; r < 4; r++) {
        const float vv = sigm(c2[r]);
        agg[0][r] += (de == 0) ? vv : 0.f;
        agg[1][r] += (de == 1) ? vv : 0.f;
        agg[2][r] += (de == 2) ? vv : 0.f;
        agg[3][r] += (de == 3) ? vv : 0.f;
        agg[4][r] += (de == 4) ? vv : 0.f;
      }
    }

    // ---- phase B: per-node update (fully unrolled: static agg indices) ----
#pragma unroll
    for (int nn = 0; nn < 5; nn++) {
      const float dr = dr_[nn];
      f4 av;
#pragma unroll
      for (int r = 0; r < 4; r++) av[r] = agg[nn][r] * dr;
      wrD(&xs[80 + m16][cD], av);           // agg -> scratch
      const int rowU = (q < 2) ? nn * 16 + 8 * q : 80 + 8 * (q - 2);
      F2 au = packAr(xb, rowU);             // [x[nn] | agg]
      f4 c = splat4(ub1n);
      c = mm(au, BU1, c);
      const float G1 = pp.upd_g1[l4 * 5 + nn] * INVC;
      const float Bb1 = pp.upd_be1[l4 * 5 + nn];
#pragma unroll
      for (int r = 0; r < 4; r++) c[r] = sigm(fmaf(G1, c[r], Bb1));
      wrD(&xs[80 + m16][cD], c);            // u1 -> scratch
      F2 a2 = packA16(xb, 80, q);
      f4 c2 = splat4(ub2n);
      c2 = mm(a2, BU2, c2);
      const float G2 = pp.upd_g2[l4 * 5 + nn] * INVC;
      const float Bb2 = pp.upd_be2[l4 * 5 + nn];
      float* xp = &xs[nn * 16 + m16][cD];
      float2 x01 = *(float2*)xp;
      float2 x23 = *(float2*)(xp + 2);
      x01.x += sigm(fmaf(G2, c2[0], Bb2));
      x01.y += sigm(fmaf(G2, c2[1], Bb2));
      x23.x += sigm(fmaf(G2, c2[2], Bb2));
      x23.y += sigm(fmaf(G2, c2[3], Bb2));
      *(float2*)xp = x01;
      *(float2*)(xp + 2) = x23;
    }
  }

  // ---------------- pooling: 3 K-tiles over 80 dims -> p1 (scratch 80-95) ----------------
  {
    f4 c = splat4(pp.bp[m16]);
    F2 a0 = packAr(xb, 8 * q);
    F2 b0 = packB<32>(pp.Wp, 16, q, m16);
    c = mm(a0, b0, c);
    F2 a1 = packAr(xb, 32 + 8 * q);
    F2 b1 = packB<32>(pp.Wp + 512, 16, q, m16);
    c = mm(a1, b1, c);
    F2 a2 = packA16(xb, 64, q);
    F2 b2 = packB<16>(pp.Wp + 1024, 16, q, m16);
    c = mm(a2, b2, c);
    const float gpn = pp.gp[m16] * INVC, bepn = pp.bep[m16];
    f4 o;
#pragma unroll
    for (int r = 0; r < 4; r++) o[r] = sigm(fmaf(gpn, c[r], bepn));
    wrD(&xs[80 + m16][cD], o);
  }

  // ---------------- mlp1: 16 -> 64 (scratch 80-95 -> rows 0-63) ----------------
  {
    F2 a = packA16(xb, 80, q);
#pragma unroll 1
    for (int nt = 0; nt < 4; nt++) {
      const int nb = nt * 16 + m16;
      F2 b = packB<16>(pp.mW1 + nt * 16, 64, q, m16);
      f4 c = splat4(pp.mb1[nb]);
      c = mm(a, b, c);
      const float g = pp.mg1[nb] * INVC, be = pp.mbe1[nb];
      f4 o;
#pragma unroll
      for (int r = 0; r < 4; r++) o[r] = sigm(fmaf(g, c[r], be));
      wrD(&xs[nt * 16 + m16][cD], o);
    }
  }
  // ---------------- mlp2: 64 -> 64 (rows 0-63 -> rows 64-127) ----------------
  {
    F2 a0 = packAr(xb, 8 * q);
    F2 a1 = packAr(xb, 32 + 8 * q);
#pragma unroll 1
    for (int nt = 0; nt < 4; nt++) {
      const int nb = nt * 16 + m16;
      F2 b0 = packB<32>(pp.mW2 + nt * 16, 64, q, m16);
      F2 b1 = packB<32>(pp.mW2 + 32 * 64 + nt * 16, 64, q, m16);
      f4 c = splat4(pp.mb2[nb]);
      c = mm(a0, b0, c);
      c = mm(a1, b1, c);
      const float g = pp.mg2[nb] * INVC, be = pp.mbe2[nb];
      f4 o;
#pragma unroll
      for (int r = 0; r < 4; r++) o[r] = sigm(fmaf(g, c[r], be));
      wrD(&xs[64 + nt * 16 + m16][cD], o);
    }
  }
  // ---------------- mlp3: 64 -> 64 (rows 64-127 -> rows 0-63) ----------------
  {
    F2 a0 = packAr(xb, 64 + 8 * q);
    F2 a1 = packAr(xb, 96 + 8 * q);
#pragma unroll 1
    for (int nt = 0; nt < 4; nt++) {
      const int nb = nt * 16 + m16;
      F2 b0 = packB<32>(pp.mW3 + nt * 16, 64, q, m16);
      F2 b1 = packB<32>(pp.mW3 + 32 * 64 + nt * 16, 64, q, m16);
      f4 c = splat4(pp.mb3[nb]);
      c = mm(a0, b0, c);
      c = mm(a1, b1, c);
      const float g = pp.mg3[nb] * INVC, be = pp.mbe3[nb];
      f4 o;
#pragma unroll
      for (int r = 0; r < 4; r++) o[r] = sigm(fmaf(g, c[r], be));
      wrD(&xs[nt * 16 + m16][cD], o);
    }
  }
  // ---------------- mlp4: 64 -> 1 (VALU dot + shfl reduce) ----------------
  {
    float s = 0.f;
#pragma unroll
    for (int j = 0; j < 16; j++)
      s = fmaf(xs[q * 16 + j][col], pp.mW4[q * 16 + j], s);
    s += __shfl_down(s, 32);
    s += __shfl_down(s, 16);
    if (l < 16) pp.out[gbase + m16] = s + pp.mb4[0];
  }
}

extern "C" void kernel_launch(void* const* d_in, const int* in_sizes, int n_in,
                              void* d_out, int out_size, void* d_ws, size_t ws_size,
                              hipStream_t stream) {
  P p;
  p.node_feat = (const float*)d_in[0];
  p.edge_feat = (const float*)d_in[1];
  p.ei        = (const int*)d_in[2];
  p.W_ne  = (const float*)d_in[3];  p.b_ne  = (const float*)d_in[4];
  p.g_ne  = (const float*)d_in[5];  p.be_ne = (const float*)d_in[6];
  p.W_ee  = (const float*)d_in[7];  p.b_ee  = (const float*)d_in[8];
  p.msg_W1 = (const float*)d_in[9];  p.msg_b1 = (const float*)d_in[10];
  p.msg_W2 = (const float*)d_in[11]; p.msg_b2 = (const float*)d_in[12];
  p.upd_W1 = (const float*)d_in[13]; p.upd_b1 = (const float*)d_in[14];
  p.upd_g1 = (const float*)d_in[15]; p.upd_be1 = (const float*)d_in[16];
  p.upd_W2 = (const float*)d_in[17]; p.upd_b2 = (const float*)d_in[18];
  p.upd_g2 = (const float*)d_in[19]; p.upd_be2 = (const float*)d_in[20];
  p.Wp  = (const float*)d_in[21]; p.bp  = (const float*)d_in[22];
  p.gp  = (const float*)d_in[23]; p.bep = (const float*)d_in[24];
  p.mW1 = (const float*)d_in[25]; p.mb1 = (const float*)d_in[26];
  p.mg1 = (const float*)d_in[27]; p.mbe1 = (const float*)d_in[28];
  p.mW2 = (const float*)d_in[29]; p.mb2 = (const float*)d_in[30];
  p.mg2 = (const float*)d_in[31]; p.mbe2 = (const float*)d_in[32];
  p.mW3 = (const float*)d_in[33]; p.mb3 = (const float*)d_in[34];
  p.mg3 = (const float*)d_in[35]; p.mbe3 = (const float*)d_in[36];
  p.mW4 = (const float*)d_in[37]; p.mb4 = (const float*)d_in[38];
  p.out = (float*)d_out;

  hipLaunchKernelGGL(gnn_kernel, dim3(NB / GPB), dim3(NT), 0, stream, p);
}